// Round 8
// baseline (549.723 us; speedup 1.0000x reference)
//
#include <hip/hip_runtime.h>
#include <hip/hip_bf16.h>

#define BBATCH 16
#define NPTS   4096
#define ROWS_PER_BLOCK 128              /* 4 waves x 32 query rows */
#define NCHUNKS 32                      /* n-chunks per (dir,batch) */
#define MCHUNK 512                      /* db points per LDS chunk */
#define NMCHUNKS 8                      /* NPTS/MCHUNK */
#define TILES 16                        /* MCHUNK/32 */

typedef unsigned short ushort_t;
typedef __attribute__((ext_vector_type(8)))  short bf16x8;
typedef __attribute__((ext_vector_type(16))) float f32x16;

__device__ __forceinline__ ushort_t bfh(float v) {
  union { __hip_bfloat16 h; ushort_t u; } c; c.h = __float2bfloat16(v); return c.u;
}
__device__ __forceinline__ float bff(ushort_t u) {
  union { ushort_t u; __hip_bfloat16 h; } c; c.u = u; return __bfloat162float(c.h);
}
__device__ __forceinline__ float min3f(float a, float b, float c) {
  return fminf(fminf(a, b), c);   // fuses to v_min3_f32
}

// K=16 bf16 record formats (hi/lo split -> f32-accurate distances):
//   A(p,s) = [ph0,ph1,ph2, pl0,pl1,pl2, ph0,ph1,ph2, sh,sl, 1,1, 0,0,0]
//   B(z,q) = [zh0,zh1,zh2, zh0,zh1,zh2, zl0,zl1,zl2, 1,1, qh,ql, 0,0,0], z=-2y
//   dot(A,B) = s + q - 2 p.y  (full squared distance; ll term negligible)

// ---------------------------------------------------------------------------
// ONE fused kernel. grid.x = 2*16*32 = 1024 blocks (4/CU, 16 waves/CU).
//   dir=0: queries = X rows, db = transformed targets (packed on the fly)
//   dir=1: queries = transformed targets, db = X points
// Per chunk: raw db points for ch+1 loaded to regs BEFORE the barrier (latency
// hidden under compute), transformed+packed to the other LDS buffer after
// compute; ONE barrier per chunk (double-buffered).
// Inner loop per tile-pair: 2 ds_read_b128 + 2 mfma_32x32x16_bf16 + 16 v_min3.
// Epilogue: 5-step lane butterfly, clamp, sum, LDS blocksum, 1 atomicAdd.
// ---------------------------------------------------------------------------
__global__ __launch_bounds__(256, 4) void chamfer_fused(
    const float* __restrict__ Xv, const float* __restrict__ Yv,
    const float* __restrict__ Tm, float* __restrict__ out)
{
  __shared__ uint4 Blds[2][2][MCHUNK];   // [buf][lo/hi][pt]  32 KB
  __shared__ float blocksum;

  const int tid = threadIdx.x, lane = tid & 63, wid = tid >> 6;
  const int kh = lane >> 5;
  const int dir = blockIdx.x >> 9;
  const int rem = blockIdx.x & 511;
  const int b   = rem >> 5;
  const int nchunk = rem & 31;

  if (tid == 0) blocksum = 0.f;

  // T (row-major [4][4]); column 3 == [0,0,0,1]^T exactly -> w==1, skip it.
  const float* T = Tm + b * 16;
  float Ta[3][3], Tt[3];
#pragma unroll
  for (int i = 0; i < 3; i++)
#pragma unroll
    for (int j = 0; j < 3; j++) Ta[i][j] = T[i*4 + j];
#pragma unroll
  for (int j = 0; j < 3; j++) Tt[j] = T[12 + j];

  const float* Qs = dir ? Yv : Xv;   // query-side raw points
  const float* Ds = dir ? Xv : Yv;   // db-side raw points
  const bool tq = (dir == 1);        // transform query side (else db side)
  const ushort_t ONE = 0x3F80;

  // ---- A fragment (this lane's kh half) ----
  bf16x8 afrag;
  {
    int qidx = b*NPTS + nchunk*ROWS_PER_BLOCK + wid*32 + (lane & 31);
    float p0 = Qs[qidx*3], p1 = Qs[qidx*3+1], p2 = Qs[qidx*3+2];
    if (tq) {
      float t0 = p0*Ta[0][0] + p1*Ta[1][0] + p2*Ta[2][0] + Tt[0];
      float t1 = p0*Ta[0][1] + p1*Ta[1][1] + p2*Ta[2][1] + Tt[1];
      float t2 = p0*Ta[0][2] + p1*Ta[1][2] + p2*Ta[2][2] + Tt[2];
      p0 = t0; p1 = t1; p2 = t2;
    }
    float sq = p0*p0 + p1*p1 + p2*p2;
    ushort_t h0=bfh(p0), h1=bfh(p1), h2=bfh(p2);
    ushort_t l0=bfh(p0-bff(h0)), l1=bfh(p1-bff(h1)), l2=bfh(p2-bff(h2));
    ushort_t sh=bfh(sq), sl=bfh(sq-bff(sh));
    union { ushort_t r[8]; bf16x8 v; } alo, ahi;
    alo.r[0]=h0; alo.r[1]=h1; alo.r[2]=h2; alo.r[3]=l0;
    alo.r[4]=l1; alo.r[5]=l2; alo.r[6]=h0; alo.r[7]=h1;
    ahi.r[0]=h2; ahi.r[1]=sh; ahi.r[2]=sl; ahi.r[3]=ONE;
    ahi.r[4]=ONE; ahi.r[5]=0; ahi.r[6]=0; ahi.r[7]=0;
    afrag = kh ? ahi.v : alo.v;
  }

  // ---- db pack: transform (dir==0 only) + hi/lo split + LDS write ----
  auto packpt = [&](int buf, int s, float r0, float r1, float r2) {
    if (!tq) {
      float t0 = r0*Ta[0][0] + r1*Ta[1][0] + r2*Ta[2][0] + Tt[0];
      float t1 = r0*Ta[0][1] + r1*Ta[1][1] + r2*Ta[2][1] + Tt[1];
      float t2 = r0*Ta[0][2] + r1*Ta[1][2] + r2*Ta[2][2] + Tt[2];
      r0 = t0; r1 = t1; r2 = t2;
    }
    float sq = r0*r0 + r1*r1 + r2*r2;
    float z0 = -2.f*r0, z1 = -2.f*r1, z2 = -2.f*r2;
    ushort_t h0=bfh(z0), h1=bfh(z1), h2=bfh(z2);
    ushort_t l0=bfh(z0-bff(h0)), l1=bfh(z1-bff(h1)), l2=bfh(z2-bff(h2));
    ushort_t sh=bfh(sq), sl=bfh(sq-bff(sh));
    union { ushort_t r[8]; uint4 q; } lo, hi;
    lo.r[0]=h0; lo.r[1]=h1; lo.r[2]=h2; lo.r[3]=h0;
    lo.r[4]=h1; lo.r[5]=h2; lo.r[6]=l0; lo.r[7]=l1;
    hi.r[0]=l2; hi.r[1]=ONE; hi.r[2]=ONE; hi.r[3]=sh;
    hi.r[4]=sl; hi.r[5]=0; hi.r[6]=0; hi.r[7]=0;
    Blds[buf][0][s] = lo.q;
    Blds[buf][1][s] = hi.q;
  };

  const float* dbase = Ds + (size_t)b * NPTS * 3;

  // prologue: stage chunk 0
  float c00 = dbase[tid*3],        c01 = dbase[tid*3+1],        c02 = dbase[tid*3+2];
  float c10 = dbase[(tid+256)*3],  c11 = dbase[(tid+256)*3+1],  c12 = dbase[(tid+256)*3+2];
  packpt(0, tid,     c00, c01, c02);
  packpt(0, tid+256, c10, c11, c12);

  float rm[16];
#pragma unroll
  for (int i = 0; i < 16; i++) rm[i] = 3e38f;

  int p = 0;
  for (int ch = 0; ch < NMCHUNKS; ++ch) {
    float n00, n01, n02, n10, n11, n12;
    if (ch + 1 < NMCHUNKS) {   // issue next-chunk raw loads (hide under compute)
      const float* nb = dbase + (size_t)(ch + 1) * MCHUNK * 3;
      n00 = nb[tid*3];       n01 = nb[tid*3+1];       n02 = nb[tid*3+2];
      n10 = nb[(tid+256)*3]; n11 = nb[(tid+256)*3+1]; n12 = nb[(tid+256)*3+2];
    }
    __syncthreads();   // buf p writes visible to all

    const bf16x8* bbase = (const bf16x8*)Blds[p][kh];
#pragma unroll
    for (int tp = 0; tp < TILES/2; ++tp) {
      int ml0 = tp * 64 + (lane & 31);
      bf16x8 b0 = bbase[ml0];
      bf16x8 b1 = bbase[ml0 + 32];
      f32x16 zc = {};
      f32x16 D0 = __builtin_amdgcn_mfma_f32_32x32x16_bf16(afrag, b0, zc, 0, 0, 0);
      f32x16 D1 = __builtin_amdgcn_mfma_f32_32x32x16_bf16(afrag, b1, zc, 0, 0, 0);
#pragma unroll
      for (int i = 0; i < 16; i++) rm[i] = min3f(rm[i], D0[i], D1[i]);
    }

    if (ch + 1 < NMCHUNKS) {   // pack next chunk into the other buffer
      packpt(p^1, tid,     n00, n01, n02);
      packpt(p^1, tid+256, n10, n11, n12);
    }
    p ^= 1;
  }

  // butterfly min over lane bits 0..4 (cols); each 32-lane half holds its 16 rows
#pragma unroll
  for (int s = 1; s <= 16; s <<= 1) {
#pragma unroll
    for (int i = 0; i < 16; i++) rm[i] = fminf(rm[i], __shfl_xor(rm[i], s, 64));
  }
  float rs = 0.f;
#pragma unroll
  for (int i = 0; i < 16; i++) rs += fmaxf(rm[i], 0.f);
  if ((lane & 31) == 0) atomicAdd(&blocksum, rs);   // lanes 0,32 = two row-halves
  __syncthreads();
  if (tid == 0) atomicAdd(out, blocksum);
}

extern "C" void kernel_launch(void* const* d_in, const int* in_sizes, int n_in,
                              void* d_out, int out_size, void* d_ws, size_t ws_size,
                              hipStream_t stream) {
  const float* Xv = (const float*)d_in[0];   // [B,N,3]
  const float* Yv = (const float*)d_in[1];   // [B,M,3]
  const float* Tm = (const float*)d_in[2];   // [B,4,4]
  float* out = (float*)d_out;

  hipMemsetAsync(out, 0, sizeof(float), stream);
  chamfer_fused<<<2 * BBATCH * NCHUNKS, 256, 0, stream>>>(Xv, Yv, Tm, out);
}

// Round 9
// 89.839 us; speedup vs baseline: 6.1190x; 6.1190x over previous
//
#include <hip/hip_runtime.h>
#include <hip/hip_bf16.h>

#define BBATCH 16
#define NPTS   4096
#define ROWS_PER_BLOCK 128              /* 4 waves x 32 query rows */
#define NCHUNKS 32                      /* n-chunks per (dir,batch) */
#define MCHUNK 512                      /* db points per LDS chunk */
#define NMCHUNKS 8                      /* NPTS/MCHUNK */
#define TILES 16                        /* MCHUNK/32 */

typedef unsigned short ushort_t;
typedef __attribute__((ext_vector_type(8)))  short bf16x8;
typedef __attribute__((ext_vector_type(16))) float f32x16;

__device__ __forceinline__ ushort_t bfh(float v) {
  union { __hip_bfloat16 h; ushort_t u; } c; c.h = __float2bfloat16(v); return c.u;
}
__device__ __forceinline__ float bff(ushort_t u) {
  union { ushort_t u; __hip_bfloat16 h; } c; c.u = u; return __bfloat162float(c.h);
}

// K=16 bf16 record formats (hi/lo split -> f32-accurate distances):
//   A(p,s) = [ph0,ph1,ph2, pl0,pl1,pl2, ph0,ph1,ph2, sh,sl, 1,1, 0,0,0]
//   B(z,q) = [zh0,zh1,zh2, zh0,zh1,zh2, zl0,zl1,zl2, 1,1, qh,ql, 0,0,0], z=-2y
//   dot(A,B) = s + q - 2 p.y  (full squared distance; ll cross term negligible)

// ---------------------------------------------------------------------------
// ONE fused kernel, register-pressure-safe version (round-8 spilled:
// launch_bounds(256,4) capped unified VGPR+AGPR at 128 -> rm[] spilled,
// 2.3 GB scratch traffic). Changes: no min-waves cap, UNPAIRED inner loop
// (one D[16] accumulator), no register prefetch (two barriers per chunk).
//   grid.x = 2*16*32 = 1024 blocks (4/CU).
//   dir=0: queries = X rows, db = transformed targets (packed on the fly)
//   dir=1: queries = transformed targets, db = X points
// Inner loop per tile: 1 ds_read_b128 + 1 mfma_32x32x16_bf16 + 16 v_min.
// Epilogue: 5-step lane butterfly, clamp, sum, LDS blocksum, 1 atomicAdd.
// D layout (m74/m101): col = lane&31 (db idx), row = (i&3)+8*(i>>2)+4*kh.
// ---------------------------------------------------------------------------
__global__ __launch_bounds__(256) void chamfer_fused(
    const float* __restrict__ Xv, const float* __restrict__ Yv,
    const float* __restrict__ Tm, float* __restrict__ out)
{
  __shared__ uint4 Blds[2][MCHUNK];   // [lo/hi][pt]  16 KB
  __shared__ float blocksum;

  const int tid = threadIdx.x, lane = tid & 63, wid = tid >> 6;
  const int kh = lane >> 5;
  const int dir = blockIdx.x >> 9;
  const int rem = blockIdx.x & 511;
  const int b   = rem >> 5;
  const int nchunk = rem & 31;

  if (tid == 0) blocksum = 0.f;

  // T is block-uniform -> lives in SGPRs. Column 3 == [0,0,0,1]^T -> w==1.
  const float* T = Tm + b * 16;

  const float* Qs = dir ? Yv : Xv;   // query-side raw points
  const float* Ds = dir ? Xv : Yv;   // db-side raw points
  const bool tq = (dir == 1);        // transform query side (else db side)
  const ushort_t ONE = 0x3F80;

  // ---- A fragment (this lane's kh half) ----
  bf16x8 afrag;
  {
    int qidx = b*NPTS + nchunk*ROWS_PER_BLOCK + wid*32 + (lane & 31);
    float p0 = Qs[qidx*3], p1 = Qs[qidx*3+1], p2 = Qs[qidx*3+2];
    if (tq) {
      float t0 = p0*T[0] + p1*T[4] + p2*T[8]  + T[12];
      float t1 = p0*T[1] + p1*T[5] + p2*T[9]  + T[13];
      float t2 = p0*T[2] + p1*T[6] + p2*T[10] + T[14];
      p0 = t0; p1 = t1; p2 = t2;
    }
    float sq = p0*p0 + p1*p1 + p2*p2;
    ushort_t h0=bfh(p0), h1=bfh(p1), h2=bfh(p2);
    ushort_t l0=bfh(p0-bff(h0)), l1=bfh(p1-bff(h1)), l2=bfh(p2-bff(h2));
    ushort_t sh=bfh(sq), sl=bfh(sq-bff(sh));
    union { ushort_t r[8]; bf16x8 v; } alo, ahi;
    alo.r[0]=h0; alo.r[1]=h1; alo.r[2]=h2; alo.r[3]=l0;
    alo.r[4]=l1; alo.r[5]=l2; alo.r[6]=h0; alo.r[7]=h1;
    ahi.r[0]=h2; ahi.r[1]=sh; ahi.r[2]=sl; ahi.r[3]=ONE;
    ahi.r[4]=ONE; ahi.r[5]=0; ahi.r[6]=0; ahi.r[7]=0;
    afrag = kh ? ahi.v : alo.v;
  }

  float rm[16];
#pragma unroll
  for (int i = 0; i < 16; i++) rm[i] = 3e38f;

  const float* dbase = Ds + (size_t)b * NPTS * 3;

  for (int ch = 0; ch < NMCHUNKS; ++ch) {
    __syncthreads();   // WAR: previous chunk's reads done before overwrite

    // pack 2 db points per thread: transform (dir==0) + hi/lo split -> LDS
#pragma unroll
    for (int half = 0; half < 2; ++half) {
      int s = tid + half * 256;
      const float* pp = dbase + (size_t)(ch * MCHUNK + s) * 3;
      float r0 = pp[0], r1 = pp[1], r2 = pp[2];
      if (!tq) {
        float t0 = r0*T[0] + r1*T[4] + r2*T[8]  + T[12];
        float t1 = r0*T[1] + r1*T[5] + r2*T[9]  + T[13];
        float t2 = r0*T[2] + r1*T[6] + r2*T[10] + T[14];
        r0 = t0; r1 = t1; r2 = t2;
      }
      float sq = r0*r0 + r1*r1 + r2*r2;
      float z0 = -2.f*r0, z1 = -2.f*r1, z2 = -2.f*r2;
      ushort_t h0=bfh(z0), h1=bfh(z1), h2=bfh(z2);
      ushort_t l0=bfh(z0-bff(h0)), l1=bfh(z1-bff(h1)), l2=bfh(z2-bff(h2));
      ushort_t sh=bfh(sq), sl=bfh(sq-bff(sh));
      union { ushort_t r[8]; uint4 q; } lo, hi;
      lo.r[0]=h0; lo.r[1]=h1; lo.r[2]=h2; lo.r[3]=h0;
      lo.r[4]=h1; lo.r[5]=h2; lo.r[6]=l0; lo.r[7]=l1;
      hi.r[0]=l2; hi.r[1]=ONE; hi.r[2]=ONE; hi.r[3]=sh;
      hi.r[4]=sl; hi.r[5]=0; hi.r[6]=0; hi.r[7]=0;
      Blds[0][s] = lo.q;
      Blds[1][s] = hi.q;
    }
    __syncthreads();

    const bf16x8* bbase = (const bf16x8*)Blds[kh];
#pragma unroll
    for (int tt = 0; tt < TILES; ++tt) {
      bf16x8 bfrag = bbase[tt * 32 + (lane & 31)];
      f32x16 zc = {};
      f32x16 D = __builtin_amdgcn_mfma_f32_32x32x16_bf16(afrag, bfrag, zc, 0, 0, 0);
#pragma unroll
      for (int i = 0; i < 16; i++) rm[i] = fminf(rm[i], D[i]);
    }
  }

  // butterfly min over lane bits 0..4 (cols); each 32-lane half holds its rows
#pragma unroll
  for (int s = 1; s <= 16; s <<= 1) {
#pragma unroll
    for (int i = 0; i < 16; i++) rm[i] = fminf(rm[i], __shfl_xor(rm[i], s, 64));
  }
  float rs = 0.f;
#pragma unroll
  for (int i = 0; i < 16; i++) rs += fmaxf(rm[i], 0.f);
  if ((lane & 31) == 0) atomicAdd(&blocksum, rs);   // lanes 0,32 = two row-halves
  __syncthreads();
  if (tid == 0) atomicAdd(out, blocksum);
}

extern "C" void kernel_launch(void* const* d_in, const int* in_sizes, int n_in,
                              void* d_out, int out_size, void* d_ws, size_t ws_size,
                              hipStream_t stream) {
  const float* Xv = (const float*)d_in[0];   // [B,N,3]
  const float* Yv = (const float*)d_in[1];   // [B,M,3]
  const float* Tm = (const float*)d_in[2];   // [B,4,4]
  float* out = (float*)d_out;

  hipMemsetAsync(out, 0, sizeof(float), stream);
  chamfer_fused<<<2 * BBATCH * NCHUNKS, 256, 0, stream>>>(Xv, Yv, Tm, out);
}

// Round 10
// 89.474 us; speedup vs baseline: 6.1440x; 1.0041x over previous
//
#include <hip/hip_runtime.h>
#include <hip/hip_bf16.h>

#define BBATCH 16
#define NPTS   4096
#define ROWS_PER_BLOCK 256              /* 4 waves x 2 afrags x 32 rows */
#define NCHUNKS 16                      /* row-chunks per (dir,batch) */
#define MCHUNK 512                      /* db points per LDS chunk */
#define NMCHUNKS 8                      /* NPTS/MCHUNK */
#define TILES 16                        /* MCHUNK/32 */

typedef unsigned short ushort_t;
typedef __attribute__((ext_vector_type(8)))  short bf16x8;
typedef __attribute__((ext_vector_type(16))) float f32x16;

__device__ __forceinline__ ushort_t bfh(float v) {
  union { __hip_bfloat16 h; ushort_t u; } c; c.h = __float2bfloat16(v); return c.u;
}
__device__ __forceinline__ float bff(ushort_t u) {
  union { ushort_t u; __hip_bfloat16 h; } c; c.u = u; return __bfloat162float(c.h);
}

// K=16 bf16 record formats (hi/lo split -> f32-accurate distances):
//   A(p,s) = [ph0,ph1,ph2, pl0,pl1,pl2, ph0,ph1,ph2, sh,sl, 1,1, 0,0,0]
//   B(z,q) = [zh0,zh1,zh2, zh0,zh1,zh2, zl0,zl1,zl2, 1,1, qh,ql, 0,0,0], z=-2y
//   dot(A,B) = s + q - 2 p.y  (missing ll cross-term ~1e-6: negligible)

// ---------------------------------------------------------------------------
// ONE fused kernel, 2-afrag version. Round-9 LDS-pipe accounting: each wave
// re-read the full chunk once per 16 MFMAs -> LDS pipe 12.8 us/CU was the
// largest budget. Two A fragments (64 query rows/wave) reuse every bfrag
// ds_read for 2 MFMAs -> LDS reads/MFMA halved; pack VALU halves too
// (2 blocks/CU instead of 4). Budgets/CU now ~6.9 MFMA / 6.8 VALU / 6.4 LDS.
//   grid.x = 2*16*16 = 512 blocks (2/CU).
//   dir=0: queries = X rows, db = transformed targets (packed on the fly)
//   dir=1: queries = transformed targets, db = X points
// Inner loop/tile: 1 ds_read_b128 + 2 mfma_32x32x16_bf16 + 32 v_min.
// Register budget (r8 spill lesson): rm0/rm1(32)+D0/D1(32)+afrags(8)+temps
// ~110 VGPR, no launch-bounds cap -> no spill.
// D layout (m74/m101): col = lane&31 (db idx), row = (i&3)+8*(i>>2)+4*kh.
// ---------------------------------------------------------------------------
__global__ __launch_bounds__(256) void chamfer_fused(
    const float* __restrict__ Xv, const float* __restrict__ Yv,
    const float* __restrict__ Tm, float* __restrict__ out)
{
  __shared__ uint4 Blds[2][MCHUNK];   // [lo/hi][pt]  16 KB
  __shared__ float blocksum;

  const int tid = threadIdx.x, lane = tid & 63, wid = tid >> 6;
  const int l31 = lane & 31, kh = lane >> 5;
  const int dir = blockIdx.x >> 8;        // 512 blocks: dir | b(4b) | nch(4b)
  const int rem = blockIdx.x & 255;
  const int b   = rem >> 4;
  const int nch = rem & 15;

  if (tid == 0) blocksum = 0.f;

  // T is block-uniform -> SGPRs. Column 3 == [0,0,0,1]^T -> w==1 exactly.
  const float* T = Tm + b * 16;

  const float* Qs = dir ? Yv : Xv;   // query-side raw points
  const float* Ds = dir ? Xv : Yv;   // db-side raw points
  const bool tq = (dir == 1);        // transform query side (else db side)
  const ushort_t ONE = 0x3F80;

  // ---- two A fragments: rows qbase+0..31 (a0) and +32..63 (a1) ----
  bf16x8 afrag0, afrag1;
#pragma unroll
  for (int a = 0; a < 2; ++a) {
    int qidx = b*NPTS + nch*ROWS_PER_BLOCK + wid*64 + a*32 + l31;
    float p0 = Qs[qidx*3], p1 = Qs[qidx*3+1], p2 = Qs[qidx*3+2];
    if (tq) {
      float t0 = p0*T[0] + p1*T[4] + p2*T[8]  + T[12];
      float t1 = p0*T[1] + p1*T[5] + p2*T[9]  + T[13];
      float t2 = p0*T[2] + p1*T[6] + p2*T[10] + T[14];
      p0 = t0; p1 = t1; p2 = t2;
    }
    float sq = p0*p0 + p1*p1 + p2*p2;
    ushort_t h0=bfh(p0), h1=bfh(p1), h2=bfh(p2);
    ushort_t l0=bfh(p0-bff(h0)), l1=bfh(p1-bff(h1)), l2=bfh(p2-bff(h2));
    ushort_t sh=bfh(sq), sl=bfh(sq-bff(sh));
    union { ushort_t r[8]; bf16x8 v; } alo, ahi;
    alo.r[0]=h0; alo.r[1]=h1; alo.r[2]=h2; alo.r[3]=l0;
    alo.r[4]=l1; alo.r[5]=l2; alo.r[6]=h0; alo.r[7]=h1;
    ahi.r[0]=h2; ahi.r[1]=sh; ahi.r[2]=sl; ahi.r[3]=ONE;
    ahi.r[4]=ONE; ahi.r[5]=0; ahi.r[6]=0; ahi.r[7]=0;
    bf16x8 f = kh ? ahi.v : alo.v;
    if (a == 0) afrag0 = f; else afrag1 = f;
  }

  float rm0[16], rm1[16];
#pragma unroll
  for (int i = 0; i < 16; i++) { rm0[i] = 3e38f; rm1[i] = 3e38f; }

  const float* dbase = Ds + (size_t)b * NPTS * 3;

  for (int ch = 0; ch < NMCHUNKS; ++ch) {
    __syncthreads();   // WAR: previous chunk's reads done before overwrite

    // pack 2 db points per thread: transform (dir==0) + hi/lo split -> LDS
#pragma unroll
    for (int half = 0; half < 2; ++half) {
      int s = tid + half * 256;
      const float* pp = dbase + (size_t)(ch * MCHUNK + s) * 3;
      float r0 = pp[0], r1 = pp[1], r2 = pp[2];
      if (!tq) {
        float t0 = r0*T[0] + r1*T[4] + r2*T[8]  + T[12];
        float t1 = r0*T[1] + r1*T[5] + r2*T[9]  + T[13];
        float t2 = r0*T[2] + r1*T[6] + r2*T[10] + T[14];
        r0 = t0; r1 = t1; r2 = t2;
      }
      float sq = r0*r0 + r1*r1 + r2*r2;
      float z0 = -2.f*r0, z1 = -2.f*r1, z2 = -2.f*r2;
      ushort_t h0=bfh(z0), h1=bfh(z1), h2=bfh(z2);
      ushort_t l0=bfh(z0-bff(h0)), l1=bfh(z1-bff(h1)), l2=bfh(z2-bff(h2));
      ushort_t sh=bfh(sq), sl=bfh(sq-bff(sh));
      union { ushort_t r[8]; uint4 q; } lo, hi;
      lo.r[0]=h0; lo.r[1]=h1; lo.r[2]=h2; lo.r[3]=h0;
      lo.r[4]=h1; lo.r[5]=h2; lo.r[6]=l0; lo.r[7]=l1;
      hi.r[0]=l2; hi.r[1]=ONE; hi.r[2]=ONE; hi.r[3]=sh;
      hi.r[4]=sl; hi.r[5]=0; hi.r[6]=0; hi.r[7]=0;
      Blds[0][s] = lo.q;
      Blds[1][s] = hi.q;
    }
    __syncthreads();

    const bf16x8* bbase = (const bf16x8*)Blds[kh];
#pragma unroll
    for (int tt = 0; tt < TILES; ++tt) {
      bf16x8 bfrag = bbase[tt * 32 + l31];
      f32x16 zc = {};
      f32x16 D0 = __builtin_amdgcn_mfma_f32_32x32x16_bf16(afrag0, bfrag, zc, 0, 0, 0);
      f32x16 D1 = __builtin_amdgcn_mfma_f32_32x32x16_bf16(afrag1, bfrag, zc, 0, 0, 0);
#pragma unroll
      for (int i = 0; i < 16; i++) {
        rm0[i] = fminf(rm0[i], D0[i]);
        rm1[i] = fminf(rm1[i], D1[i]);
      }
    }
  }

  // butterfly min over lane bits 0..4 (cols); each 32-lane half holds its rows
#pragma unroll
  for (int s = 1; s <= 16; s <<= 1) {
#pragma unroll
    for (int i = 0; i < 16; i++) {
      rm0[i] = fminf(rm0[i], __shfl_xor(rm0[i], s, 64));
      rm1[i] = fminf(rm1[i], __shfl_xor(rm1[i], s, 64));
    }
  }
  float rs = 0.f;
#pragma unroll
  for (int i = 0; i < 16; i++) rs += fmaxf(rm0[i], 0.f) + fmaxf(rm1[i], 0.f);
  if (l31 == 0) atomicAdd(&blocksum, rs);   // lanes 0,32 = the two row-halves
  __syncthreads();
  if (tid == 0) atomicAdd(out, blocksum);
}

extern "C" void kernel_launch(void* const* d_in, const int* in_sizes, int n_in,
                              void* d_out, int out_size, void* d_ws, size_t ws_size,
                              hipStream_t stream) {
  const float* Xv = (const float*)d_in[0];   // [B,N,3]
  const float* Yv = (const float*)d_in[1];   // [B,M,3]
  const float* Tm = (const float*)d_in[2];   // [B,4,4]
  float* out = (float*)d_out;

  hipMemsetAsync(out, 0, sizeof(float), stream);
  chamfer_fused<<<2 * BBATCH * NCHUNKS, 256, 0, stream>>>(Xv, Yv, Tm, out);
}